// Round 8
// baseline (360.014 us; speedup 1.0000x reference)
//
#include <hip/hip_runtime.h>
#include <math.h>

// KNN-attention: N=50000, K=16 neighbors, HIDDEN=256 = 8 heads x 32 dim.
// One wave64 per point: lane owns float4 at col = 4*lane; a wave's gather of
// one K/V row = contiguous 1KB (fully coalesced).
//
// Round-8 root-cause fix: __launch_bounds__(256) defaulted the compiler to an
// 8-waves/EU occupancy target => ~64-VGPR budget => every attempt to keep 16
// gathers in flight (plain code, sched_barrier, memory clobber, even inline
// asm) was defeated by pressure-driven sinking/AGPR-spilling (VGPR stuck at
// 56 across rounds 1-7). __launch_bounds__(256, 4) grants a 128-VGPR budget
// (4 waves/EU = 16 waves/CU), and the volatile-asm gathers guarantee issue
// order: 16 loads in flight per phase, one s_waitcnt vmcnt(0) per phase.
// Kernel renamed to knn_attn_r8 as a stale-build canary.

#define KNN_K      16
#define HIDDEN_    256
#define SCALE_     0.17677669529663687f   // 32^-0.5

typedef float f32x4 __attribute__((ext_vector_type(4)));

__global__ __launch_bounds__(256, 4) void knn_attn_r8(
    const float* __restrict__ keys,
    const float* __restrict__ queries,
    const float* __restrict__ values,
    const int*   __restrict__ nbr,
    float*       __restrict__ out,
    int n_pts)
{
    const int gtid = blockIdx.x * blockDim.x + threadIdx.x;
    const int pt   = gtid >> 6;            // one wave64 per point
    const int lane = threadIdx.x & 63;
    if (pt >= n_pts) return;               // 50000*64 == 12500*256: no ragged waves

    const unsigned lane16 = (unsigned)lane << 4;   // byte offset of lane's float4

    // Wave-uniform neighbor indices -> SGPRs (readfirstlane), freeing VGPRs
    // and enabling saddr-form loads (32-bit voffset + SGPR base).
    const int4* nb4 = reinterpret_cast<const int4*>(nbr + (size_t)pt * KNN_K);
    const int4 i0 = nb4[0], i1 = nb4[1], i2 = nb4[2], i3 = nb4[3];
    int idx[KNN_K] = { i0.x,i0.y,i0.z,i0.w, i1.x,i1.y,i1.z,i1.w,
                       i2.x,i2.y,i2.z,i2.w, i3.x,i3.y,i3.z,i3.w };
    #pragma unroll
    for (int k = 0; k < KNN_K; ++k)
        idx[k] = __builtin_amdgcn_readfirstlane(idx[k]);

    const float4 q4 = *reinterpret_cast<const float4*>(
        queries + (size_t)pt * HIDDEN_ + (lane << 2));

    // ---- phase 1: 16 K-row gathers in flight (volatile asm = fixed order) ----
    f32x4 kr[KNN_K];
    #pragma unroll
    for (int k = 0; k < KNN_K; ++k) {
        const unsigned off = ((unsigned)idx[k] << 10) + lane16;  // idx*1024 + lane*16
        asm volatile("global_load_dwordx4 %0, %1, %2"
                     : "=v"(kr[k]) : "v"(off), "s"(keys));
    }
    asm volatile("s_waitcnt vmcnt(0)" ::: "memory");
    __builtin_amdgcn_sched_barrier(0);   // consumers may not hoist above the wait

    // Per-lane partial dots; kr dies here (its 64 VGPRs recycle into vr).
    float s[KNN_K];
    #pragma unroll
    for (int k = 0; k < KNN_K; ++k)
        s[k] = q4.x * kr[k].x + q4.y * kr[k].y
             + q4.z * kr[k].z + q4.w * kr[k].w;

    // ---- phase 2: issue 16 V-row gathers; reduce+softmax hides their latency ----
    f32x4 vr[KNN_K];
    #pragma unroll
    for (int k = 0; k < KNN_K; ++k) {
        const unsigned off = ((unsigned)idx[k] << 10) + lane16;  // same layout as K
        asm volatile("global_load_dwordx4 %0, %1, %2"
                     : "=v"(vr[k]) : "v"(off), "s"(values));
    }

    // Cross-lane reduce within each aligned 8-lane head group (lgkm, not vm).
    #pragma unroll
    for (int k = 0; k < KNN_K; ++k) {
        float p = s[k];
        p += __shfl_xor(p, 1, 64);
        p += __shfl_xor(p, 2, 64);
        p += __shfl_xor(p, 4, 64);
        s[k] = p * SCALE_;
    }

    // Softmax over K=16 in registers; normalize once at the end.
    float m = s[0];
    #pragma unroll
    for (int k = 1; k < KNN_K; ++k) m = fmaxf(m, s[k]);
    float denom = 0.f;
    #pragma unroll
    for (int k = 0; k < KNN_K; ++k) { s[k] = __expf(s[k] - m); denom += s[k]; }
    const float inv = 1.0f / denom;

    asm volatile("s_waitcnt vmcnt(0)" ::: "memory");
    __builtin_amdgcn_sched_barrier(0);   // vr consumers stay below the wait

    float4 acc = make_float4(0.f, 0.f, 0.f, 0.f);
    #pragma unroll
    for (int k = 0; k < KNN_K; ++k) {
        acc.x += s[k] * vr[k].x; acc.y += s[k] * vr[k].y;
        acc.z += s[k] * vr[k].z; acc.w += s[k] * vr[k].w;
    }
    acc.x *= inv; acc.y *= inv; acc.z *= inv; acc.w *= inv;

    *reinterpret_cast<float4*>(out + (size_t)pt * HIDDEN_ + (lane << 2)) = acc;
}

extern "C" void kernel_launch(void* const* d_in, const int* in_sizes, int n_in,
                              void* d_out, int out_size, void* d_ws, size_t ws_size,
                              hipStream_t stream) {
    const float* keys    = (const float*)d_in[0];
    const float* queries = (const float*)d_in[1];
    const float* values  = (const float*)d_in[2];
    const int*   nbr     = (const int*)d_in[3];
    float*       out     = (float*)d_out;

    const int n_pts = in_sizes[3] / KNN_K;       // 50000
    const int waves_per_block = 4;               // 256 threads
    const int blocks = (n_pts + waves_per_block - 1) / waves_per_block;
    knn_attn_r8<<<blocks, 256, 0, stream>>>(keys, queries, values, nbr, out, n_pts);
}

// Round 9
// 278.794 us; speedup vs baseline: 1.2913x; 1.2913x over previous
//
#include <hip/hip_runtime.h>
#include <math.h>

// KNN-attention: N=50000, K=16 neighbors, HIDDEN=256 = 8 heads x 32 dim.
//
// Rounds 1-8: five structurally different kernels (plain, hoisted, sched_barrier,
// memory-clobber, inline-asm gathers, launch_bounds(256,4)) ALL land at 243+-2us
// with identical counters. That flatness = throughput wall, not scheduling:
// L1-side gather traffic 1.6GB/244us = 6.7 TB/s, L2-miss 796MB/244us = 3.5 TB/s.
// Round-9 experiment: halve the bytes. Pre-convert K,V to bf16 in d_ws (rows
// become 512B), gather bf16. BW-wall hypothesis => gather time halves.
// Latency hypothesis => unchanged (same request count). Discriminating test
// that is also the likely win.

#define KNN_K      16
#define HIDDEN_    256
#define SCALE_     0.17677669529663687f   // 32^-0.5

typedef unsigned short u16;

// ---- f32 -> bf16 with round-to-nearest-even (bit trick, no lib calls) ----
__device__ __forceinline__ u16 f2bf(float f) {
    unsigned u = __float_as_uint(f);
    unsigned r = (u + 0x7FFFu + ((u >> 16) & 1u)) >> 16;
    return (u16)r;
}
__device__ __forceinline__ float bf_lo(unsigned w) {   // low 16 bits -> f32
    return __uint_as_float(w << 16);
}
__device__ __forceinline__ float bf_hi(unsigned w) {   // high 16 bits -> f32
    return __uint_as_float(w & 0xFFFF0000u);
}

// ---- streaming convert: float4 -> 4x bf16 (8B) ----
__global__ __launch_bounds__(256) void cvt_bf16_kernel(
    const float4* __restrict__ src, ushort4* __restrict__ dst, int n4)
{
    int i      = blockIdx.x * blockDim.x + threadIdx.x;
    int stride = gridDim.x * blockDim.x;
    for (; i < n4; i += stride) {
        const float4 v = src[i];
        ushort4 o;
        o.x = f2bf(v.x); o.y = f2bf(v.y); o.z = f2bf(v.z); o.w = f2bf(v.w);
        dst[i] = o;
    }
}

// ---- main: one wave64 per point; lane owns 4 dims (8B bf16 per gathered row) ----
__global__ __launch_bounds__(256, 4) void knn_attn_bf16_r9(
    const u16*   __restrict__ kbf,      // [N][256] bf16 rows (512B)
    const float* __restrict__ queries,  // [N][256] f32
    const u16*   __restrict__ vbf,      // [N][256] bf16 rows
    const int*   __restrict__ nbr,
    float*       __restrict__ out,
    int n_pts)
{
    const int gtid = blockIdx.x * blockDim.x + threadIdx.x;
    const int pt   = gtid >> 6;            // one wave64 per point
    const int lane = threadIdx.x & 63;
    if (pt >= n_pts) return;

    // Wave-uniform neighbor indices: broadcast int4 fetches.
    const int4* nb4 = reinterpret_cast<const int4*>(nbr + (size_t)pt * KNN_K);
    const int4 i0 = nb4[0], i1 = nb4[1], i2 = nb4[2], i3 = nb4[3];
    const int idx[KNN_K] = { i0.x,i0.y,i0.z,i0.w, i1.x,i1.y,i1.z,i1.w,
                             i2.x,i2.y,i2.z,i2.w, i3.x,i3.y,i3.z,i3.w };

    // Lane's 4 query dims (f32, coalesced float4).
    const float4 q4 = *reinterpret_cast<const float4*>(
        queries + (size_t)pt * HIDDEN_ + (lane << 2));

    // ---- K phase: 16 gathered uint2 (8B = 4 bf16) per lane; only 32 VGPRs of
    // payload, well under the 128-VGPR budget -> compiler free to batch loads.
    const uint2* kbase = reinterpret_cast<const uint2*>(kbf);
    uint2 kr[KNN_K];
    #pragma unroll
    for (int k = 0; k < KNN_K; ++k)
        kr[k] = kbase[(size_t)idx[k] * 64 + lane];   // 64 uint2 per 512B row

    float s[KNN_K];
    #pragma unroll
    for (int k = 0; k < KNN_K; ++k) {
        s[k] = q4.x * bf_lo(kr[k].x) + q4.y * bf_hi(kr[k].x)
             + q4.z * bf_lo(kr[k].y) + q4.w * bf_hi(kr[k].y);
    }

    // ---- V phase issued before the reduce so its latency hides under it.
    const uint2* vbase = reinterpret_cast<const uint2*>(vbf);
    uint2 vr[KNN_K];
    #pragma unroll
    for (int k = 0; k < KNN_K; ++k)
        vr[k] = vbase[(size_t)idx[k] * 64 + lane];

    // Cross-lane reduce within each aligned 8-lane head group.
    #pragma unroll
    for (int k = 0; k < KNN_K; ++k) {
        float p = s[k];
        p += __shfl_xor(p, 1, 64);
        p += __shfl_xor(p, 2, 64);
        p += __shfl_xor(p, 4, 64);
        s[k] = p * SCALE_;
    }

    // Softmax over K=16 in registers; normalize once at the end.
    float m = s[0];
    #pragma unroll
    for (int k = 1; k < KNN_K; ++k) m = fmaxf(m, s[k]);
    float denom = 0.f;
    #pragma unroll
    for (int k = 0; k < KNN_K; ++k) { s[k] = __expf(s[k] - m); denom += s[k]; }
    const float inv = 1.0f / denom;

    float4 acc = make_float4(0.f, 0.f, 0.f, 0.f);
    #pragma unroll
    for (int k = 0; k < KNN_K; ++k) {
        acc.x += s[k] * bf_lo(vr[k].x); acc.y += s[k] * bf_hi(vr[k].x);
        acc.z += s[k] * bf_lo(vr[k].y); acc.w += s[k] * bf_hi(vr[k].y);
    }
    acc.x *= inv; acc.y *= inv; acc.z *= inv; acc.w *= inv;

    *reinterpret_cast<float4*>(out + (size_t)pt * HIDDEN_ + (lane << 2)) = acc;
}

// ---- fallback: plain f32 gather (round-1 kernel) if ws too small ----
__global__ __launch_bounds__(256) void knn_attn_f32_fb(
    const float* __restrict__ keys,
    const float* __restrict__ queries,
    const float* __restrict__ values,
    const int*   __restrict__ nbr,
    float*       __restrict__ out,
    int n_pts)
{
    const int gtid = blockIdx.x * blockDim.x + threadIdx.x;
    const int pt   = gtid >> 6;
    const int lane = threadIdx.x & 63;
    if (pt >= n_pts) return;

    const int4* nb4 = reinterpret_cast<const int4*>(nbr + (size_t)pt * KNN_K);
    const int4 i0 = nb4[0], i1 = nb4[1], i2 = nb4[2], i3 = nb4[3];
    const int idx[KNN_K] = { i0.x,i0.y,i0.z,i0.w, i1.x,i1.y,i1.z,i1.w,
                             i2.x,i2.y,i2.z,i2.w, i3.x,i3.y,i3.z,i3.w };

    const float4 q4 = *reinterpret_cast<const float4*>(
        queries + (size_t)pt * HIDDEN_ + (lane << 2));

    float s[KNN_K];
    #pragma unroll
    for (int k = 0; k < KNN_K; ++k) {
        const float4 k4 = *reinterpret_cast<const float4*>(
            keys + (size_t)idx[k] * HIDDEN_ + (lane << 2));
        float p = q4.x * k4.x + q4.y * k4.y + q4.z * k4.z + q4.w * k4.w;
        p += __shfl_xor(p, 1, 64);
        p += __shfl_xor(p, 2, 64);
        p += __shfl_xor(p, 4, 64);
        s[k] = p * SCALE_;
    }
    float m = s[0];
    #pragma unroll
    for (int k = 1; k < KNN_K; ++k) m = fmaxf(m, s[k]);
    float denom = 0.f;
    #pragma unroll
    for (int k = 0; k < KNN_K; ++k) { s[k] = __expf(s[k] - m); denom += s[k]; }
    const float inv = 1.0f / denom;

    float4 acc = make_float4(0.f, 0.f, 0.f, 0.f);
    #pragma unroll
    for (int k = 0; k < KNN_K; ++k) {
        const float4 v4 = *reinterpret_cast<const float4*>(
            values + (size_t)idx[k] * HIDDEN_ + (lane << 2));
        acc.x += s[k] * v4.x; acc.y += s[k] * v4.y;
        acc.z += s[k] * v4.z; acc.w += s[k] * v4.w;
    }
    acc.x *= inv; acc.y *= inv; acc.z *= inv; acc.w *= inv;

    *reinterpret_cast<float4*>(out + (size_t)pt * HIDDEN_ + (lane << 2)) = acc;
}

extern "C" void kernel_launch(void* const* d_in, const int* in_sizes, int n_in,
                              void* d_out, int out_size, void* d_ws, size_t ws_size,
                              hipStream_t stream) {
    const float* keys    = (const float*)d_in[0];
    const float* queries = (const float*)d_in[1];
    const float* values  = (const float*)d_in[2];
    const int*   nbr     = (const int*)d_in[3];
    float*       out     = (float*)d_out;

    const int n_pts  = in_sizes[3] / KNN_K;          // 50000
    const int blocks = (n_pts * 64 + 255) / 256;     // one wave per point

    const size_t elems    = (size_t)n_pts * HIDDEN_; // 12.8M per tensor
    const size_t bf_bytes = elems * sizeof(u16);     // 25.6 MB per tensor

    if (ws_size >= 2 * bf_bytes) {
        u16* kbf = (u16*)d_ws;
        u16* vbf = (u16*)((char*)d_ws + bf_bytes);

        const int n4        = (int)(elems / 4);      // 3.2M float4 groups
        const int cvt_grid  = 2048;                  // grid-stride
        cvt_bf16_kernel<<<cvt_grid, 256, 0, stream>>>(
            (const float4*)keys,   (ushort4*)kbf, n4);
        cvt_bf16_kernel<<<cvt_grid, 256, 0, stream>>>(
            (const float4*)values, (ushort4*)vbf, n4);

        knn_attn_bf16_r9<<<blocks, 256, 0, stream>>>(
            kbf, queries, vbf, nbr, out, n_pts);
    } else {
        knn_attn_f32_fb<<<blocks, 256, 0, stream>>>(
            keys, queries, values, nbr, out, n_pts);
    }
}